// Round 9
// baseline (38.459 us; speedup 1.0000x reference)
//
#include <hip/hip_runtime.h>
#include <hip/hip_bf16.h>

// Problem constants
#define BB 32   // batch
#define NN 512  // ragged items (reduced axis)
#define SS 32   // static input size (rows per token tile)
#define WW 64   // attention layer width (K of GEMM1, also hidden width)
#define PP 64   // layer param (output features)

typedef __attribute__((ext_vector_type(8))) short bf16x8;  // 8 bf16 (4 VGPRs)
typedef __attribute__((ext_vector_type(4))) float f32x4;   // MFMA acc / vec loads

typedef __attribute__((address_space(1))) const void* as1cv;
typedef __attribute__((address_space(3))) void* as3v;

// f32 -> bf16 via native cast; compiler emits v_cvt_pk_bf16_f32 pairs
__device__ __forceinline__ short f2bf(float v) {
    __hip_bfloat16 h = __float2bfloat16(v);
    return __builtin_bit_cast(short, h);
}

// Single fused kernel. Block = (b, sg): owns output rows b*32 + sg*4 .. +3 and
// streams ALL 512 tokens' 4-row slices (1 KB/token, contiguous). 256 blocks =
// exactly 1/CU (32/XCD). 4 waves x 128 tokens each; A-tile = 4 tokens x 4 rows
// (16 rows); D-row = 4*g + r maps to (token=g, s_row=r) so the token-sum is a
// per-lane accumulate + one shfl_xor(16)+shfl_xor(32) reduce at the end.
// Epilogue applies W2 in fp32 and writes out directly: 1 dispatch, no ws.
__global__ __launch_bounds__(256) void pooler(const float* __restrict__ x,
                                              const float* __restrict__ W1,
                                              const float* __restrict__ b1,
                                              const float* __restrict__ W2,
                                              const float* __restrict__ b2,
                                              float* __restrict__ out) {
    __shared__ float stg[4][4][1024];   // 64 KiB: [wave][4-deep dbuf][4KB tile]

    const int tid  = threadIdx.x;
    const int wv   = tid >> 6;
    const int lane = tid & 63;
    const int g    = lane >> 4;       // lane group 0..3
    const int q    = lane & 15;
    const int b  = blockIdx.x >> 3;   // 8 s-groups per b
    const int sg = blockIdx.x & 7;

    // W1 fragments (B operand): wfrag[nt][ks] elem j = W1[ks*32+g*8+j][nt*16+q]
    bf16x8 wfrag[4][2];
#pragma unroll
    for (int nt = 0; nt < 4; ++nt) {
#pragma unroll
        for (int ks = 0; ks < 2; ++ks) {
            bf16x8 f;
#pragma unroll
            for (int j = 0; j < 8; ++j)
                f[j] = f2bf(W1[(ks * 32 + g * 8 + j) * WW + nt * 16 + q]);
            wfrag[nt][ks] = f;
        }
    }

    // bias for D col = nt*16+q (same for all 4 acc regs)
    float bias[4];
#pragma unroll
    for (int nt = 0; nt < 4; ++nt) bias[nt] = b1[nt * 16 + q];

    // hrun[nt][r]: per-lane partial sum over this lane-group's tokens
    f32x4 hrun[4];
#pragma unroll
    for (int nt = 0; nt < 4; ++nt) hrun[nt] = (f32x4){0.f, 0.f, 0.f, 0.f};

    // clean vmem slate so counted vmcnt below is exact
    asm volatile("s_waitcnt vmcnt(0)" ::: "memory");
    __builtin_amdgcn_sched_barrier(0);

    // token t's 4-row slice starts at x[b][t][sg*4][0]: 256 floats contiguous
    const float* base0 = x + ((size_t)b * NN) * (SS * WW) + (sg * 4) * WW;

    // stage tile j of this wave (tokens wv*128 + j*4 + k): 4 x global_load_lds,
    // each one contiguous 1KB wave request (lane L -> 16B at slice + L*16)
    auto STAGE = [&](int buf, int j) {
#pragma unroll
        for (int k = 0; k < 4; ++k) {
            const float* src = base0 + ((size_t)(wv * 128 + j * 4 + k)) * (SS * WW) + lane * 4;
            __builtin_amdgcn_global_load_lds((as1cv)src, (as3v)&stg[wv][buf][k * 256],
                                             16, 0, 0);
        }
    };

    // consume one staged tile: A row i = q <-> (token q>>2, s q&3) at byte q*256
    auto COMPUTE = [&](int buf) {
        const char* base = (const char*)&stg[wv][buf][0];
        bf16x8 afrag[2];
#pragma unroll
        for (int ks = 0; ks < 2; ++ks) {
            const unsigned o = (unsigned)(q * 256 + ks * 128 + g * 32);
            f32x4 lo = *reinterpret_cast<const f32x4*>(base + o);
            f32x4 hi = *reinterpret_cast<const f32x4*>(base + o + 16);
            bf16x8 f;
            f[0] = f2bf(lo[0]); f[1] = f2bf(lo[1]); f[2] = f2bf(lo[2]); f[3] = f2bf(lo[3]);
            f[4] = f2bf(hi[0]); f[5] = f2bf(hi[1]); f[6] = f2bf(hi[2]); f[7] = f2bf(hi[3]);
            afrag[ks] = f;
        }
#pragma unroll
        for (int nt = 0; nt < 4; ++nt) {
            float bv = bias[nt];
            f32x4 acc = (f32x4){bv, bv, bv, bv};
            acc = __builtin_amdgcn_mfma_f32_16x16x32_bf16(afrag[0], wfrag[nt][0], acc, 0, 0, 0);
            acc = __builtin_amdgcn_mfma_f32_16x16x32_bf16(afrag[1], wfrag[nt][1], acc, 0, 0, 0);
#pragma unroll
            for (int r = 0; r < 4; ++r)
                hrun[nt][r] += fmaxf(acc[r], 0.f);
        }
    };

    STAGE(0, 0); STAGE(1, 1); STAGE(2, 2); STAGE(3, 3);
#pragma unroll
    for (int j = 0; j < 32; ++j) {
        if (j < 28)       { asm volatile("s_waitcnt vmcnt(12)" ::: "memory"); }
        else if (j == 28) { asm volatile("s_waitcnt vmcnt(0)"  ::: "memory"); }
        __builtin_amdgcn_sched_barrier(0);
        COMPUTE(j & 3);
        if (j < 28) STAGE(j & 3, j + 4);
    }

    // cross-g reduce (lanes q, q+16, q+32, q+48 hold same (r, col)) then LDS
    float* red = &stg[wv][0][0];   // 4x64 floats per wave, reuse stage buffer
#pragma unroll
    for (int nt = 0; nt < 4; ++nt) {
#pragma unroll
        for (int r = 0; r < 4; ++r) {
            float v = hrun[nt][r];
            v += __shfl_xor(v, 16);
            v += __shfl_xor(v, 32);
            if (lane < 16) red[r * WW + nt * 16 + q] = v;
        }
    }
    __syncthreads();

    // epilogue: out[row, p] = sum_w h[r][w] * W2[w][p] + NN*b2[p]
    const int r = tid >> 6;        // == wv
    const int p = tid & 63;
    float acc = (float)NN * b2[p];
#pragma unroll
    for (int w = 0; w < WW; ++w) {
        float hw = (stg[0][0][r * WW + w] + stg[1][0][r * WW + w]) +
                   (stg[2][0][r * WW + w] + stg[3][0][r * WW + w]);
        acc = fmaf(hw, W2[w * PP + p], acc);
    }
    out[((b * SS) + sg * 4 + r) * PP + p] = acc;
}

extern "C" void kernel_launch(void* const* d_in, const int* in_sizes, int n_in,
                              void* d_out, int out_size, void* d_ws, size_t ws_size,
                              hipStream_t stream) {
    const float* x  = (const float*)d_in[0];
    const float* W1 = (const float*)d_in[1];
    const float* b1 = (const float*)d_in[2];
    const float* W2 = (const float*)d_in[3];
    const float* b2 = (const float*)d_in[4];
    float* out = (float*)d_out;

    pooler<<<dim3(BB * 8), dim3(256), 0, stream>>>(x, W1, b1, W2, b2, out);
}

// Round 10
// 32.058 us; speedup vs baseline: 1.1997x; 1.1997x over previous
//
#include <hip/hip_runtime.h>
#include <hip/hip_bf16.h>

// Problem constants
#define BB 32   // batch
#define NN 512  // ragged items (reduced axis)
#define SS 32   // static input size (rows per token tile)
#define WW 64   // attention layer width (K of GEMM1, also hidden width)
#define PP 64   // layer param (output features)

#define NCHUNK 16              // n's per block (4 tokens per wave)
#define CHB    (NN / NCHUNK)   // 32 chunks per b

typedef __attribute__((ext_vector_type(8))) short bf16x8;  // 8 bf16 (4 VGPRs)
typedef __attribute__((ext_vector_type(8))) short short8;
typedef __attribute__((ext_vector_type(4))) float f32x4;   // MFMA acc / vec loads

typedef __attribute__((address_space(1))) const void* as1cv;
typedef __attribute__((address_space(3))) void* as3v;

// f32 -> bf16 via native cast; compiler emits v_cvt_pk_bf16_f32 pairs
__device__ __forceinline__ short f2bf(float v) {
    __hip_bfloat16 h = __float2bfloat16(v);
    return __builtin_bit_cast(short, h);
}
__device__ __forceinline__ float bf2f(unsigned short u) {
    return __builtin_bit_cast(float, ((unsigned)u) << 16);
}

// Kernel 1: h-partials for chunk c of batch b:
//   part[b][s][c][w] = bf16( sum_{n in chunk} relu(x[b,n,s,:] @ W1[:,w] + b1[w]) )
// 1024 blocks x 256 threads (4 waves), 4 tokens/wave; per-wave private LDS
// double buffer filled by global_load_lds (16B/lane, linear contiguous 1KB
// wave spans), counted vmcnt(8) waits. Identical streaming structure to the
// 33.0us R6 kernel; only the part store (bf16, [b][s][c][w]) changed.
__global__ __launch_bounds__(256) void pool1(const float* __restrict__ x,
                                             const float* __restrict__ W1,
                                             const float* __restrict__ b1,
                                             unsigned short* __restrict__ part) {
    __shared__ float stg[4][2][2048];   // 64 KiB: [wave][dbuf][8KB token image]

    const int tid  = threadIdx.x;
    const int wv   = tid >> 6;
    const int lane = tid & 63;
    const int g    = lane >> 4;       // lane group 0..3
    const int q    = lane & 15;
    const int b     = blockIdx.x >> 5;   // CHB == 32
    const int chunk = blockIdx.x & 31;

    // W1 fragments (B operand): wfrag[nt][ks] elem j = W1[ks*32+g*8+j][nt*16+q]
    bf16x8 wfrag[4][2];
#pragma unroll
    for (int nt = 0; nt < 4; ++nt) {
#pragma unroll
        for (int ks = 0; ks < 2; ++ks) {
            bf16x8 f;
#pragma unroll
            for (int j = 0; j < 8; ++j)
                f[j] = f2bf(W1[(ks * 32 + g * 8 + j) * WW + nt * 16 + q]);
            wfrag[nt][ks] = f;
        }
    }

    // bias for D col = nt*16+q (same for all 4 acc regs)
    float bias[4];
#pragma unroll
    for (int nt = 0; nt < 4; ++nt) bias[nt] = b1[nt * 16 + q];

    f32x4 hrun[2][4];
#pragma unroll
    for (int mt = 0; mt < 2; ++mt)
#pragma unroll
        for (int nt = 0; nt < 4; ++nt)
            hrun[mt][nt] = (f32x4){0.f, 0.f, 0.f, 0.f};

    // clean vmem slate so counted vmcnt below is exact
    asm volatile("s_waitcnt vmcnt(0)" ::: "memory");
    __builtin_amdgcn_sched_barrier(0);

    const float* tok0 = x + ((size_t)(b * NN + chunk * NCHUNK + wv * 4)) * (SS * WW);

    // stage token t into stg[wv][dbuf]: 8 x global_load_lds, each one
    // contiguous 1KB wave request (lane L -> bytes [k*1024 + L*16, +16))
    auto STAGE = [&](int dbuf, int t) {
        const float* tbase = tok0 + (size_t)t * (SS * WW);
#pragma unroll
        for (int k = 0; k < 8; ++k) {
            const float* src = tbase + k * 256 + lane * 4;
            __builtin_amdgcn_global_load_lds((as1cv)src, (as3v)&stg[wv][dbuf][k * 256],
                                             16, 0, 0);
        }
    };

    // consume one staged token: fragment-gather ds_read_b128, cvt, 8 MFMA, relu-acc
    auto COMPUTE = [&](int dbuf) {
        const char* base = (const char*)&stg[wv][dbuf][0];
        bf16x8 afrag[2][2];
#pragma unroll
        for (int mt = 0; mt < 2; ++mt) {
#pragma unroll
            for (int ks = 0; ks < 2; ++ks) {
                // afrag elem j = x[row = mt*16+q][col = ks*32 + g*8 + j]
                const unsigned o = (unsigned)((mt * 16 + q) * 256 + ks * 128 + g * 32);
                f32x4 lo = *reinterpret_cast<const f32x4*>(base + o);
                f32x4 hi = *reinterpret_cast<const f32x4*>(base + o + 16);
                bf16x8 f;
                f[0] = f2bf(lo[0]); f[1] = f2bf(lo[1]); f[2] = f2bf(lo[2]); f[3] = f2bf(lo[3]);
                f[4] = f2bf(hi[0]); f[5] = f2bf(hi[1]); f[6] = f2bf(hi[2]); f[7] = f2bf(hi[3]);
                afrag[mt][ks] = f;
            }
        }
#pragma unroll
        for (int mt = 0; mt < 2; ++mt) {
#pragma unroll
            for (int nt = 0; nt < 4; ++nt) {
                float bv = bias[nt];
                f32x4 acc = (f32x4){bv, bv, bv, bv};
                acc = __builtin_amdgcn_mfma_f32_16x16x32_bf16(afrag[mt][0], wfrag[nt][0], acc, 0, 0, 0);
                acc = __builtin_amdgcn_mfma_f32_16x16x32_bf16(afrag[mt][1], wfrag[nt][1], acc, 0, 0, 0);
#pragma unroll
                for (int r = 0; r < 4; ++r)
                    hrun[mt][nt][r] += fmaxf(acc[r], 0.f);
            }
        }
    };

    STAGE(0, 0);
    STAGE(1, 1);
    asm volatile("s_waitcnt vmcnt(8)" ::: "memory");   // tok0 landed
    __builtin_amdgcn_sched_barrier(0);
    COMPUTE(0);
    STAGE(0, 2);
    asm volatile("s_waitcnt vmcnt(8)" ::: "memory");   // tok1 landed
    __builtin_amdgcn_sched_barrier(0);
    COMPUTE(1);
    STAGE(1, 3);
    asm volatile("s_waitcnt vmcnt(8)" ::: "memory");   // tok2 landed
    __builtin_amdgcn_sched_barrier(0);
    COMPUTE(0);
    asm volatile("s_waitcnt vmcnt(0)" ::: "memory");   // tok3 landed
    __builtin_amdgcn_sched_barrier(0);
    COMPUTE(1);

    // cross-wave reduce: reuse stg[wv][0] (8KB/wave) as the reduce buffer
    float* red = &stg[wv][0][0];
#pragma unroll
    for (int mt = 0; mt < 2; ++mt)
#pragma unroll
        for (int nt = 0; nt < 4; ++nt)
#pragma unroll
            for (int r = 0; r < 4; ++r)
                red[(mt * 16 + g * 4 + r) * WW + nt * 16 + q] = hrun[mt][nt][r];
    __syncthreads();

    // pack to bf16 and store: thread -> (s_row = tid>>3, w-octet = tid&7)
    // dst layout [b][s][c][w]: pool2 then reads a contiguous 4KB per row.
    {
        const int s_row = tid >> 3;
        const int w0    = (tid & 7) * 8;
        f32x4 a0 = *reinterpret_cast<const f32x4*>(&stg[0][0][s_row * WW + w0]);
        f32x4 a1 = *reinterpret_cast<const f32x4*>(&stg[1][0][s_row * WW + w0]);
        f32x4 a2 = *reinterpret_cast<const f32x4*>(&stg[2][0][s_row * WW + w0]);
        f32x4 a3 = *reinterpret_cast<const f32x4*>(&stg[3][0][s_row * WW + w0]);
        f32x4 b0 = *reinterpret_cast<const f32x4*>(&stg[0][0][s_row * WW + w0 + 4]);
        f32x4 b1v = *reinterpret_cast<const f32x4*>(&stg[1][0][s_row * WW + w0 + 4]);
        f32x4 b2v = *reinterpret_cast<const f32x4*>(&stg[2][0][s_row * WW + w0 + 4]);
        f32x4 b3 = *reinterpret_cast<const f32x4*>(&stg[3][0][s_row * WW + w0 + 4]);
        f32x4 sa = (a0 + a1) + (a2 + a3);
        f32x4 sb = (b0 + b1v) + (b2v + b3);
        short8 pk;
        pk[0] = f2bf(sa[0]); pk[1] = f2bf(sa[1]); pk[2] = f2bf(sa[2]); pk[3] = f2bf(sa[3]);
        pk[4] = f2bf(sb[0]); pk[5] = f2bf(sb[1]); pk[6] = f2bf(sb[2]); pk[7] = f2bf(sb[3]);
        unsigned short* dst = part + ((((size_t)b * SS + s_row) * CHB) + chunk) * WW + w0;
        *reinterpret_cast<short8*>(dst) = pk;
    }
}

// Kernel 2: out[b,s,p] = sum_w (sum_c part[b][s][c][w]) * W2[w,p] + NN * b2[p]
// 1024 blocks (one per output row); the row's 32x64 bf16 tile is contiguous
// (4KB). 4 waves split the 32-chunk reduction, wave 0 does the 64x64 matvec.
__global__ __launch_bounds__(256) void pool2(const unsigned short* __restrict__ part,
                                             const float* __restrict__ W2,
                                             const float* __restrict__ b2,
                                             float* __restrict__ out) {
    const int tid  = threadIdx.x;
    const int wv   = tid >> 6;
    const int lane = tid & 63;
    const int row  = blockIdx.x;        // b*SS + s

    const unsigned short* pb = part + (size_t)row * (CHB * WW) + lane;
    float h = 0.f;
#pragma unroll
    for (int c = 0; c < CHB / 4; ++c)
        h += bf2f(pb[(wv * (CHB / 4) + c) * WW]);

    __shared__ float hs[4][WW];
    hs[wv][lane] = h;
    __syncthreads();

    if (wv == 0) {
        float acc = (float)NN * b2[lane];
#pragma unroll
        for (int w = 0; w < WW; ++w) {
            float hw = (hs[0][w] + hs[1][w]) + (hs[2][w] + hs[3][w]);
            acc = fmaf(hw, W2[w * PP + lane], acc);
        }
        out[row * PP + lane] = acc;
    }
}

extern "C" void kernel_launch(void* const* d_in, const int* in_sizes, int n_in,
                              void* d_out, int out_size, void* d_ws, size_t ws_size,
                              hipStream_t stream) {
    const float* x  = (const float*)d_in[0];
    const float* W1 = (const float*)d_in[1];
    const float* b1 = (const float*)d_in[2];
    const float* W2 = (const float*)d_in[3];
    const float* b2 = (const float*)d_in[4];
    float* out = (float*)d_out;
    unsigned short* part = (unsigned short*)d_ws;  // [b][s][c][w] bf16 = 4 MiB

    pool1<<<dim3(BB * CHB), dim3(256), 0, stream>>>(x, W1, b1, part);
    pool2<<<dim3(BB * SS), dim3(256), 0, stream>>>(part, W2, b2, out);
}

// Round 11
// 31.205 us; speedup vs baseline: 1.2325x; 1.0273x over previous
//
#include <hip/hip_runtime.h>
#include <hip/hip_bf16.h>

// Problem constants
#define BB 32   // batch
#define NN 512  // ragged items (reduced axis)
#define SS 32   // static input size (rows per token tile)
#define WW 64   // attention layer width (K of GEMM1, also hidden width)
#define PP 64   // layer param (output features)

#define NCHUNK 16              // n's per block (4 tokens per wave)
#define CHB    (NN / NCHUNK)   // 32 chunks per b

typedef __attribute__((ext_vector_type(8))) short bf16x8;  // 8 bf16 (4 VGPRs)
typedef __attribute__((ext_vector_type(8))) short short8;
typedef __attribute__((ext_vector_type(4))) float f32x4;   // MFMA acc / vec loads

typedef __attribute__((address_space(1))) const void* as1cv;
typedef __attribute__((address_space(3))) void* as3v;

// f32 -> bf16 via native cast; compiler emits v_cvt_pk_bf16_f32 pairs
__device__ __forceinline__ short f2bf(float v) {
    __hip_bfloat16 h = __float2bfloat16(v);
    return __builtin_bit_cast(short, h);
}
__device__ __forceinline__ float bf2f(unsigned short u) {
    return __builtin_bit_cast(float, ((unsigned)u) << 16);
}

// Kernel 1: h-partials for chunk c of batch b:
//   part[b][s][c][w] = bf16( sum_{n in chunk} relu(x[b,n,s,:] @ W1[:,w] + b1[w]) )
// 1024 blocks x 256 threads (4 waves), 4 tokens/wave; per-wave private LDS
// double buffer filled by global_load_lds (16B/lane, linear contiguous 1KB
// wave spans), counted vmcnt(8) waits. vs R10: the first two STAGEs issue
// BEFORE the W1/bias gather, so W1 latency hides under tok0/tok1 staging
// (tok loads are OLDER in the in-order vm counter, so the loop's counted
// waits remain exact; the post-gather vmcnt(0) = "entire prologue landed").
__global__ __launch_bounds__(256) void pool1(const float* __restrict__ x,
                                             const float* __restrict__ W1,
                                             const float* __restrict__ b1,
                                             unsigned short* __restrict__ part) {
    __shared__ float stg[4][2][2048];   // 64 KiB: [wave][dbuf][8KB token image]

    const int tid  = threadIdx.x;
    const int wv   = tid >> 6;
    const int lane = tid & 63;
    const int g    = lane >> 4;       // lane group 0..3
    const int q    = lane & 15;
    const int b     = blockIdx.x >> 5;   // CHB == 32
    const int chunk = blockIdx.x & 31;

    const float* tok0 = x + ((size_t)(b * NN + chunk * NCHUNK + wv * 4)) * (SS * WW);

    // stage token t into stg[wv][dbuf]: 8 x global_load_lds, each one
    // contiguous 1KB wave request (lane L -> bytes [k*1024 + L*16, +16))
    auto STAGE = [&](int dbuf, int t) {
        const float* tbase = tok0 + (size_t)t * (SS * WW);
#pragma unroll
        for (int k = 0; k < 8; ++k) {
            const float* src = tbase + k * 256 + lane * 4;
            __builtin_amdgcn_global_load_lds((as1cv)src, (as3v)&stg[wv][dbuf][k * 256],
                                             16, 0, 0);
        }
    };

    // issue the first two token stages FIRST — x streaming starts immediately
    STAGE(0, 0);
    STAGE(1, 1);

    // W1 fragments (B operand): wfrag[nt][ks] elem j = W1[ks*32+g*8+j][nt*16+q]
    bf16x8 wfrag[4][2];
#pragma unroll
    for (int nt = 0; nt < 4; ++nt) {
#pragma unroll
        for (int ks = 0; ks < 2; ++ks) {
            bf16x8 f;
#pragma unroll
            for (int j = 0; j < 8; ++j)
                f[j] = f2bf(W1[(ks * 32 + g * 8 + j) * WW + nt * 16 + q]);
            wfrag[nt][ks] = f;
        }
    }

    // bias for D col = nt*16+q (same for all 4 acc regs)
    float bias[4];
#pragma unroll
    for (int nt = 0; nt < 4; ++nt) bias[nt] = b1[nt * 16 + q];
    // force bias materialized here (no compiler-deferred vmem wait inside loop)
#pragma unroll
    for (int nt = 0; nt < 4; ++nt) asm volatile("" : "+v"(bias[nt]));

    f32x4 hrun[2][4];
#pragma unroll
    for (int mt = 0; mt < 2; ++mt)
#pragma unroll
        for (int nt = 0; nt < 4; ++nt)
            hrun[mt][nt] = (f32x4){0.f, 0.f, 0.f, 0.f};

    // prologue landed: W1/bias in regs, tok0/tok1 in LDS; counter now 0
    asm volatile("s_waitcnt vmcnt(0)" ::: "memory");
    __builtin_amdgcn_sched_barrier(0);

    // consume one staged token: fragment-gather ds_read_b128, cvt, 8 MFMA, relu-acc
    auto COMPUTE = [&](int dbuf) {
        const char* base = (const char*)&stg[wv][dbuf][0];
        bf16x8 afrag[2][2];
#pragma unroll
        for (int mt = 0; mt < 2; ++mt) {
#pragma unroll
            for (int ks = 0; ks < 2; ++ks) {
                // afrag elem j = x[row = mt*16+q][col = ks*32 + g*8 + j]
                const unsigned o = (unsigned)((mt * 16 + q) * 256 + ks * 128 + g * 32);
                f32x4 lo = *reinterpret_cast<const f32x4*>(base + o);
                f32x4 hi = *reinterpret_cast<const f32x4*>(base + o + 16);
                bf16x8 f;
                f[0] = f2bf(lo[0]); f[1] = f2bf(lo[1]); f[2] = f2bf(lo[2]); f[3] = f2bf(lo[3]);
                f[4] = f2bf(hi[0]); f[5] = f2bf(hi[1]); f[6] = f2bf(hi[2]); f[7] = f2bf(hi[3]);
                afrag[mt][ks] = f;
            }
        }
#pragma unroll
        for (int mt = 0; mt < 2; ++mt) {
#pragma unroll
            for (int nt = 0; nt < 4; ++nt) {
                float bv = bias[nt];
                f32x4 acc = (f32x4){bv, bv, bv, bv};
                acc = __builtin_amdgcn_mfma_f32_16x16x32_bf16(afrag[mt][0], wfrag[nt][0], acc, 0, 0, 0);
                acc = __builtin_amdgcn_mfma_f32_16x16x32_bf16(afrag[mt][1], wfrag[nt][1], acc, 0, 0, 0);
#pragma unroll
                for (int r = 0; r < 4; ++r)
                    hrun[mt][nt][r] += fmaxf(acc[r], 0.f);
            }
        }
    };

    COMPUTE(0);                                        // tok0 resident
    STAGE(0, 2);
    asm volatile("s_waitcnt vmcnt(8)" ::: "memory");   // tok1 landed (no-op-ish)
    __builtin_amdgcn_sched_barrier(0);
    COMPUTE(1);
    STAGE(1, 3);
    asm volatile("s_waitcnt vmcnt(8)" ::: "memory");   // tok2 landed
    __builtin_amdgcn_sched_barrier(0);
    COMPUTE(0);
    asm volatile("s_waitcnt vmcnt(0)" ::: "memory");   // tok3 landed
    __builtin_amdgcn_sched_barrier(0);
    COMPUTE(1);

    // cross-wave reduce: reuse stg[wv][0] (8KB/wave) as the reduce buffer
    float* red = &stg[wv][0][0];
#pragma unroll
    for (int mt = 0; mt < 2; ++mt)
#pragma unroll
        for (int nt = 0; nt < 4; ++nt)
#pragma unroll
            for (int r = 0; r < 4; ++r)
                red[(mt * 16 + g * 4 + r) * WW + nt * 16 + q] = hrun[mt][nt][r];
    __syncthreads();

    // pack to bf16 and store: thread -> (s_row = tid>>3, w-octet = tid&7)
    // dst layout [b][s][c][w]: pool2 then reads a contiguous 4KB per row.
    {
        const int s_row = tid >> 3;
        const int w0    = (tid & 7) * 8;
        f32x4 a0 = *reinterpret_cast<const f32x4*>(&stg[0][0][s_row * WW + w0]);
        f32x4 a1 = *reinterpret_cast<const f32x4*>(&stg[1][0][s_row * WW + w0]);
        f32x4 a2 = *reinterpret_cast<const f32x4*>(&stg[2][0][s_row * WW + w0]);
        f32x4 a3 = *reinterpret_cast<const f32x4*>(&stg[3][0][s_row * WW + w0]);
        f32x4 b0 = *reinterpret_cast<const f32x4*>(&stg[0][0][s_row * WW + w0 + 4]);
        f32x4 b1v = *reinterpret_cast<const f32x4*>(&stg[1][0][s_row * WW + w0 + 4]);
        f32x4 b2v = *reinterpret_cast<const f32x4*>(&stg[2][0][s_row * WW + w0 + 4]);
        f32x4 b3 = *reinterpret_cast<const f32x4*>(&stg[3][0][s_row * WW + w0 + 4]);
        f32x4 sa = (a0 + a1) + (a2 + a3);
        f32x4 sb = (b0 + b1v) + (b2v + b3);
        short8 pk;
        pk[0] = f2bf(sa[0]); pk[1] = f2bf(sa[1]); pk[2] = f2bf(sa[2]); pk[3] = f2bf(sa[3]);
        pk[4] = f2bf(sb[0]); pk[5] = f2bf(sb[1]); pk[6] = f2bf(sb[2]); pk[7] = f2bf(sb[3]);
        unsigned short* dst = part + ((((size_t)b * SS + s_row) * CHB) + chunk) * WW + w0;
        *reinterpret_cast<short8*>(dst) = pk;
    }
}

// Kernel 2: out[b,s,p] = sum_w (sum_c part[b][s][c][w]) * W2[w,p] + NN * b2[p]
// 1024 blocks (one per output row); the row's 32x64 bf16 tile is contiguous
// (4KB). 4 waves split the 32-chunk reduction, wave 0 does the 64x64 matvec.
__global__ __launch_bounds__(256) void pool2(const unsigned short* __restrict__ part,
                                             const float* __restrict__ W2,
                                             const float* __restrict__ b2,
                                             float* __restrict__ out) {
    const int tid  = threadIdx.x;
    const int wv   = tid >> 6;
    const int lane = tid & 63;
    const int row  = blockIdx.x;        // b*SS + s

    const unsigned short* pb = part + (size_t)row * (CHB * WW) + lane;
    float h = 0.f;
#pragma unroll
    for (int c = 0; c < CHB / 4; ++c)
        h += bf2f(pb[(wv * (CHB / 4) + c) * WW]);

    __shared__ float hs[4][WW];
    hs[wv][lane] = h;
    __syncthreads();

    if (wv == 0) {
        float acc = (float)NN * b2[lane];
#pragma unroll
        for (int w = 0; w < WW; ++w) {
            float hw = (hs[0][w] + hs[1][w]) + (hs[2][w] + hs[3][w]);
            acc = fmaf(hw, W2[w * PP + lane], acc);
        }
        out[row * PP + lane] = acc;
    }
}

extern "C" void kernel_launch(void* const* d_in, const int* in_sizes, int n_in,
                              void* d_out, int out_size, void* d_ws, size_t ws_size,
                              hipStream_t stream) {
    const float* x  = (const float*)d_in[0];
    const float* W1 = (const float*)d_in[1];
    const float* b1 = (const float*)d_in[2];
    const float* W2 = (const float*)d_in[3];
    const float* b2 = (const float*)d_in[4];
    float* out = (float*)d_out;
    unsigned short* part = (unsigned short*)d_ws;  // [b][s][c][w] bf16 = 4 MiB

    pool1<<<dim3(BB * CHB), dim3(256), 0, stream>>>(x, W1, b1, part);
    pool2<<<dim3(BB * SS), dim3(256), 0, stream>>>(part, W2, b2, out);
}